// Round 11
// baseline (235.439 us; speedup 1.0000x reference)
//
#include <hip/hip_runtime.h>
#include <hip/hip_fp16.h>

#define BLANKC 59
#define NEGF (-1e30f)
#define RS 400      // LDS emission-row stride in halves (16B-aligned, 4-way b128)
#define TTILE 64

typedef _Float16 half8 __attribute__((ext_vector_type(8)));

// Wave-wide shift-right-by-1 via DPP (lane 0 gets `fill`). VALU-speed.
__device__ __forceinline__ float wave_shr1(float x, float fill) {
    int r = __builtin_amdgcn_update_dpp(__float_as_int(fill), __float_as_int(x),
                                        0x138 /* WAVE_SHR:1 */, 0xF, 0xF, false);
    return __int_as_float(r);
}

// ---------------- Fused CTC: one block per batch element --------------------
// Phase A (all 256 threads): build logp emission table for all T=384 steps
//   directly in LDS: S[slot][t], slot l = logp[lab[l]], slot 45 = logp[BLANK].
// Phase B (wave 0 only): R8's log-domain alpha recurrence (proven correct).
__global__ __launch_bounds__(256)
void ctc_fused(const int* __restrict__ labels, const float* __restrict__ logits,
               float* __restrict__ out, int T, int V, int L, float inv_b) {
    const int b   = blockIdx.x;
    const int tid = threadIdx.x;

    __shared__ __align__(16) __half S[46 * RS];          // 36.8 KB
    __shared__ float ftile[TTILE][61];                   // 15.6 KB, stride 61

    const float* src = logits + (long)b * T * V;
    const int*   lab = labels + (long)b * L;

    // ---------------- Phase A: 6 tiles of 64 time steps ----------------
    for (int tile = 0; tile < T / TTILE; ++tile) {
        const float* tsrc = src + tile * TTILE * 60;     // 3840 contiguous floats
        #pragma unroll
        for (int it = 0; it < 15; ++it) {
            const int idx = it * 256 + tid;
            const int r = idx / 60, c = idx - r * 60;
            ftile[r][c] = tsrc[idx];
        }
        __syncthreads();

        {   // LSE + gather: 4 lanes per t (within-wave quad groups)
            const int tl = tid >> 2;                     // local t 0..63
            const int q  = tid & 3;
            const int tg = tile * TTILE + tl;            // global t
            float s = 0.f;
            #pragma unroll
            for (int k = 0; k < 15; ++k) s += __expf(ftile[tl][q * 15 + k]);
            s += __shfl_xor(s, 1, 64);
            s += __shfl_xor(s, 2, 64);
            const float lse = __logf(s);
            #pragma unroll
            for (int j = 0; j < 12; ++j) {
                const int l = q * 12 + j;
                if (l < 46) {
                    const int v = (l < 45) ? lab[l] : BLANKC;
                    S[l * RS + tg] = __float2half(ftile[tl][v] - lse);
                }
            }
        }
        __syncthreads();                                 // WAR before next tile
    }

    // ---------------- Phase B: log-domain recurrence, wave 0 only -------
    if (tid < 64) {
        const int lane = tid;
        const int labL = (lane < L) ? lab[lane] : BLANKC;
        const int labP = (lane >= 1 && lane < L) ? lab[lane - 1] : BLANKC;
        const bool skip = (lane >= 1) && (lane < L) && (labL != BLANKC) && (labL != labP);

        unsigned long long mk = __ballot((lane < L) && (labL != BLANKC));
        const int len = __popcll(mk);

        const int li = (lane < 46) ? lane : 45;
        const __half* rowL = &S[li * RS];                // lane's slot row
        const __half* rowB = &S[45 * RS];                // blank row (uniform)

        half8 curL = *(const half8*)(rowL);
        half8 curB = *(const half8*)(rowB);

        float a0 = (lane == 0) ? (float)curB[0] : NEGF;  // s=0: blank @ t=0
        float a1 = (lane == 0) ? (float)curL[0] : NEGF;  // s=1: first label @ t=0
        float m01 = fmaxf(a0, a1);                       // off-chain hoist

        auto step = [&](float eL, float eB) {
            const float p  = wave_shr1(a1, NEGF);        // alpha_old[2l-1]
            const float ps = skip ? p : NEGF;
            const float m0 = fmaxf(a0, p);
            const float na0 = m0 + __logf(__expf(a0 - m0) + __expf(p - m0)) + eB;
            const float m1 = fmaxf(m01, ps);
            const float na1 = m1 + __logf(__expf(a1 - m1) + __expf(a0 - m1) + __expf(ps - m1)) + eL;
            a0 = na0; a1 = na1;
            m01 = fmaxf(na0, na1);
        };

        // chunk 0: t = 1..7
        #pragma unroll
        for (int i = 1; i < 8; ++i) step((float)curL[i], (float)curB[i]);

        const int NSEG = T / 8;                          // 48
        for (int c = 1; c < NSEG; ++c) {
            const half8 nL = *(const half8*)(rowL + c * 8);
            const half8 nB = *(const half8*)(rowB + c * 8);
            #pragma unroll
            for (int i = 0; i < 8; ++i) step((float)nL[i], (float)nB[i]);
        }

        // epilogue: end = 2*len -> lane len's a0; end-1 -> lane (len-1)'s a1
        const float ab2 = __shfl(a0, len, 64);
        float al2 = __shfl(a1, (len > 0) ? len - 1 : 0, 64);
        al2 = (len > 0) ? al2 : NEGF;
        if (lane == 0) {
            const float mm  = fmaxf(ab2, al2);
            const float nll = -(mm + __logf(__expf(ab2 - mm) + __expf(al2 - mm)));
            atomicAdd(out, nll * inv_b);
        }
    }
}

extern "C" void kernel_launch(void* const* d_in, const int* in_sizes, int n_in,
                              void* d_out, int out_size, void* d_ws, size_t ws_size,
                              hipStream_t stream) {
    const int* labels   = (const int*)d_in[0];
    const float* logits = (const float*)d_in[1];
    float* out          = (float*)d_out;

    const int L = 45, V = 60;
    const int B = in_sizes[0] / L;
    const int T = in_sizes[1] / (B * V);

    (void)hipMemsetAsync(out, 0, (size_t)out_size * sizeof(float), stream);
    ctc_fused<<<B, 256, 0, stream>>>(labels, logits, out, T, V, L, 1.0f / (float)B);
}